// Round 1
// baseline (324.977 us; speedup 1.0000x reference)
//
#include <hip/hip_runtime.h>
#include <hip/hip_bf16.h>

// Shapes (fixed by the reference): T=16384 rows of H, J=1024 rows of U, D2=512.
#define T_ROWS 16384
#define J_DIM  1024
#define D_DIM  512

typedef __attribute__((ext_vector_type(8))) short bf16x8;   // 8 bf16 (4 VGPRs) MFMA A/B frag
typedef __attribute__((ext_vector_type(4))) float f32x4;    // MFMA C/D frag

__device__ inline unsigned short f2bf(float f) {
    union { float f; unsigned int u; } v; v.f = f;
    unsigned int r = (v.u + 0x7FFFu + ((v.u >> 16) & 1u)) >> 16;  // RNE
    return (unsigned short)r;
}

// ---------------------------------------------------------------------------
// K0: per-row of U: uw2[j] = U_j . w2 ; Ub = bf16(U) [J][D]; UtB = bf16(U^T) [D][J]
// ---------------------------------------------------------------------------
__global__ __launch_bounds__(128) void prep_kernel(
    const float* __restrict__ U, const float* __restrict__ Ws,
    float* __restrict__ uw2, short* __restrict__ Ub, short* __restrict__ UtB)
{
    const int j = blockIdx.x;
    const int t = threadIdx.x;
    const float4 u  = ((const float4*)(U + (size_t)j * D_DIM))[t];
    const float4 w2 = ((const float4*)(Ws + D_DIM))[t];
    float p = u.x * w2.x + u.y * w2.y + u.z * w2.z + u.w * w2.w;
    #pragma unroll
    for (int m = 1; m < 64; m <<= 1) p += __shfl_xor(p, m);
    __shared__ float red[2];
    if ((t & 63) == 0) red[t >> 6] = p;
    __syncthreads();
    if (t == 0) uw2[j] = red[0] + red[1];

    short4 ub;
    ub.x = (short)f2bf(u.x); ub.y = (short)f2bf(u.y);
    ub.z = (short)f2bf(u.z); ub.w = (short)f2bf(u.w);
    ((short4*)(Ub + (size_t)j * D_DIM))[t] = ub;
    UtB[(size_t)(4 * t + 0) * J_DIM + j] = ub.x;
    UtB[(size_t)(4 * t + 1) * J_DIM + j] = ub.y;
    UtB[(size_t)(4 * t + 2) * J_DIM + j] = ub.z;
    UtB[(size_t)(4 * t + 3) * J_DIM + j] = ub.w;
}

// ---------------------------------------------------------------------------
// K1: fused  S = (H.w3) @ Ub^T + uw2  -> row softmax -> AQ = P @ U
//     One block = 16 H rows; 4 waves. S phase: waves split j (256 each).
//     PV phase: waves split d (128 each). S row tile lives in LDS (XOR-swizzled).
//     Also emits rstat[i] = hw1_i + max_j(S'_ij) for the global b-softmax.
// ---------------------------------------------------------------------------
__global__ __launch_bounds__(256) void attn_kernel(
    const float* __restrict__ H, const float* __restrict__ Ws,
    const float* __restrict__ uw2, const short* __restrict__ Ub,
    const short* __restrict__ UtB, float* __restrict__ rstat,
    float* __restrict__ out)
{
    __shared__ float S[16][1024];   // 64 KB, element index XOR-swizzled by ((row&7)<<2)
    __shared__ float inv_l[16];
    __shared__ float hw1_s[16];

    const int tid  = threadIdx.x;
    const int w    = tid >> 6;
    const int lane = tid & 63;
    const int fr   = lane & 15;    // frag row/col (A-row, B-row, C-col)
    const int quad = lane >> 4;    // k-chunk selector
    const int ib   = blockIdx.x * 16;

    // ---- Step 1: Q fragments (bf16 of H*w3) into registers; hw1 partial ----
    bf16x8 qf[16];
    float hw1p = 0.f;
    const float* hrow = H + (size_t)(ib + fr) * D_DIM;
    #pragma unroll
    for (int ks = 0; ks < 16; ++ks) {
        const int k0 = ks * 32 + quad * 8;
        float4 a   = *(const float4*)(hrow + k0);
        float4 b   = *(const float4*)(hrow + k0 + 4);
        float4 w3a = *(const float4*)(Ws + 2 * D_DIM + k0);
        float4 w3b = *(const float4*)(Ws + 2 * D_DIM + k0 + 4);
        float4 w1a = *(const float4*)(Ws + k0);
        float4 w1b = *(const float4*)(Ws + k0 + 4);
        hw1p += a.x*w1a.x + a.y*w1a.y + a.z*w1a.z + a.w*w1a.w
              + b.x*w1b.x + b.y*w1b.y + b.z*w1b.z + b.w*w1b.w;
        qf[ks][0] = (short)f2bf(a.x * w3a.x);
        qf[ks][1] = (short)f2bf(a.y * w3a.y);
        qf[ks][2] = (short)f2bf(a.z * w3a.z);
        qf[ks][3] = (short)f2bf(a.w * w3a.w);
        qf[ks][4] = (short)f2bf(b.x * w3b.x);
        qf[ks][5] = (short)f2bf(b.y * w3b.y);
        qf[ks][6] = (short)f2bf(b.z * w3b.z);
        qf[ks][7] = (short)f2bf(b.w * w3b.w);
    }
    if (w == 0) {
        float h1 = hw1p + __shfl_xor(hw1p, 16);
        h1 += __shfl_xor(h1, 32);
        if (quad == 0) hw1_s[fr] = h1;
    }

    // ---- Step 2: S tile, this wave's 256 j-columns ----
    #pragma unroll 2
    for (int jt = 0; jt < 16; ++jt) {
        const int j0 = w * 256 + jt * 16;
        f32x4 acc = (f32x4){0.f, 0.f, 0.f, 0.f};
        const short* bbase = Ub + (size_t)(j0 + fr) * D_DIM + quad * 8;
        #pragma unroll
        for (int ks = 0; ks < 16; ++ks) {
            bf16x8 bf = *(const bf16x8*)(bbase + ks * 32);
            acc = __builtin_amdgcn_mfma_f32_16x16x32_bf16(qf[ks], bf, acc, 0, 0, 0);
        }
        const int jj = j0 + fr;          // C col = lane&15
        const float u2 = uw2[jj];
        #pragma unroll
        for (int m = 0; m < 4; ++m) {
            const int rr = quad * 4 + m; // C row
            S[rr][jj ^ ((rr & 7) << 2)] = acc[m] + u2;
        }
    }
    __syncthreads();

    // ---- Step 3: row softmax over 1024 (16 threads per row) ----
    {
        const int rr = tid >> 4;
        const int c  = tid & 15;
        const int sw = (rr & 7) << 2;
        float mx = -1e30f;
        for (int it = 0; it < 64; ++it)
            mx = fmaxf(mx, S[rr][(c + it * 16) ^ sw]);
        mx = fmaxf(mx, __shfl_xor(mx, 1));
        mx = fmaxf(mx, __shfl_xor(mx, 2));
        mx = fmaxf(mx, __shfl_xor(mx, 4));
        mx = fmaxf(mx, __shfl_xor(mx, 8));
        float l = 0.f;
        for (int it = 0; it < 64; ++it) {
            const int idx = (c + it * 16) ^ sw;
            const float e = __expf(S[rr][idx] - mx);
            S[rr][idx] = e;
            l += e;
        }
        l += __shfl_xor(l, 1); l += __shfl_xor(l, 2);
        l += __shfl_xor(l, 4); l += __shfl_xor(l, 8);
        if (c == 0) {
            inv_l[rr] = 1.f / l;
            rstat[ib + rr] = mx + hw1_s[rr];
        }
    }
    __syncthreads();

    // ---- Step 4: AQ = P @ U, this wave's 128 d-columns ----
    f32x4 acc[8];
    #pragma unroll
    for (int dt = 0; dt < 8; ++dt) acc[dt] = (f32x4){0.f, 0.f, 0.f, 0.f};

    const int sw = (fr & 7) << 2;
    const float il = inv_l[fr];
    #pragma unroll 4
    for (int ks = 0; ks < 32; ++ks) {
        const int jb = ks * 32 + quad * 8;
        const float4 v0 = *(const float4*)&S[fr][jb ^ sw];
        const float4 v1 = *(const float4*)&S[fr][(jb + 4) ^ sw];
        bf16x8 pf;
        pf[0] = (short)f2bf(v0.x * il);
        pf[1] = (short)f2bf(v0.y * il);
        pf[2] = (short)f2bf(v0.z * il);
        pf[3] = (short)f2bf(v0.w * il);
        pf[4] = (short)f2bf(v1.x * il);
        pf[5] = (short)f2bf(v1.y * il);
        pf[6] = (short)f2bf(v1.z * il);
        pf[7] = (short)f2bf(v1.w * il);
        #pragma unroll
        for (int dt = 0; dt < 8; ++dt) {
            const bf16x8 bf = *(const bf16x8*)(UtB + (size_t)(w * 128 + dt * 16 + fr) * J_DIM + jb);
            acc[dt] = __builtin_amdgcn_mfma_f32_16x16x32_bf16(pf, bf, acc[dt], 0, 0, 0);
        }
    }
    #pragma unroll
    for (int dt = 0; dt < 8; ++dt)
        #pragma unroll
        for (int m = 0; m < 4; ++m)
            out[(size_t)(ib + quad * 4 + m) * 2048 + 512 + w * 128 + dt * 16 + fr] = acc[dt][m];
}

// ---------------------------------------------------------------------------
// K2: b = softmax(rstat) over all 16384 rows (single block, deterministic)
// ---------------------------------------------------------------------------
__global__ __launch_bounds__(1024) void bsoft_kernel(
    const float* __restrict__ r, float* __restrict__ b)
{
    __shared__ float red[16];
    __shared__ float Msh, Lsh;
    const int t = threadIdx.x;
    float m = -1e30f;
    #pragma unroll
    for (int e = 0; e < 16; ++e) m = fmaxf(m, r[t + e * 1024]);
    #pragma unroll
    for (int s = 1; s < 64; s <<= 1) m = fmaxf(m, __shfl_xor(m, s));
    if ((t & 63) == 0) red[t >> 6] = m;
    __syncthreads();
    if (t == 0) {
        float M = red[0];
        for (int i = 1; i < 16; ++i) M = fmaxf(M, red[i]);
        Msh = M;
    }
    __syncthreads();
    const float M = Msh;
    float l = 0.f;
    #pragma unroll
    for (int e = 0; e < 16; ++e) l += __expf(r[t + e * 1024] - M);
    #pragma unroll
    for (int s = 1; s < 64; s <<= 1) l += __shfl_xor(l, s);
    if ((t & 63) == 0) red[t >> 6] = l;
    __syncthreads();
    if (t == 0) {
        float L = 0.f;
        for (int i = 0; i < 16; ++i) L += red[i];
        Lsh = L;
    }
    __syncthreads();
    const float invL = 1.f / Lsh;
    #pragma unroll
    for (int e = 0; e < 16; ++e) b[t + e * 1024] = __expf(r[t + e * 1024] - M) * invL;
}

// ---------------------------------------------------------------------------
// K3a/K3b: h_tilde = b @ H  (deterministic two-stage reduction)
// ---------------------------------------------------------------------------
__global__ __launch_bounds__(512) void htilde_partial(
    const float* __restrict__ H, const float* __restrict__ b,
    float* __restrict__ part)
{
    const int blk = blockIdx.x;      // 256 blocks x 64 rows
    const int d = threadIdx.x;
    const int i0 = blk * 64;
    float s = 0.f;
    for (int rI = 0; rI < 64; ++rI)
        s += b[i0 + rI] * H[(size_t)(i0 + rI) * D_DIM + d];
    part[(size_t)blk * D_DIM + d] = s;
}

__global__ __launch_bounds__(512) void htilde_reduce(
    const float* __restrict__ part, float* __restrict__ ht)
{
    const int d = threadIdx.x;
    float s = 0.f;
    for (int p = 0; p < 256; ++p) s += part[(size_t)p * D_DIM + d];
    ht[d] = s;
}

// ---------------------------------------------------------------------------
// K4: assemble G = [H, AQ, H*AQ, H*h_tilde]  (AQ already in place from K1)
// ---------------------------------------------------------------------------
__global__ __launch_bounds__(128) void assemble_kernel(
    const float* __restrict__ H, const float* __restrict__ ht,
    float* __restrict__ out)
{
    const int i = blockIdx.x;
    const int t = threadIdx.x;               // 128 float4s = 512 floats
    const float4 h  = ((const float4*)(H + (size_t)i * D_DIM))[t];
    const float4 aq = ((const float4*)(out + (size_t)i * 2048 + 512))[t];
    const float4 hv = ((const float4*)ht)[t];
    float4 ha, hh;
    ha.x = h.x * aq.x; ha.y = h.y * aq.y; ha.z = h.z * aq.z; ha.w = h.w * aq.w;
    hh.x = h.x * hv.x; hh.y = h.y * hv.y; hh.z = h.z * hv.z; hh.w = h.w * hv.w;
    ((float4*)(out + (size_t)i * 2048))[t] = h;
    ((float4*)(out + (size_t)i * 2048 + 1024))[t] = ha;
    ((float4*)(out + (size_t)i * 2048 + 1536))[t] = hh;
}

// ---------------------------------------------------------------------------
extern "C" void kernel_launch(void* const* d_in, const int* in_sizes, int n_in,
                              void* d_out, int out_size, void* d_ws, size_t ws_size,
                              hipStream_t stream)
{
    const float* H  = (const float*)d_in[0];
    const float* U  = (const float*)d_in[1];
    const float* Ws = (const float*)d_in[2];
    float* out = (float*)d_out;

    float* uw2   = (float*)d_ws;            // 1024
    float* rstat = uw2 + 1024;              // 16384
    float* bvec  = rstat + T_ROWS;          // 16384
    float* htld  = bvec + T_ROWS;           // 512
    float* part  = htld + D_DIM;            // 256*512
    short* Ub    = (short*)(part + 256 * D_DIM);   // J*D bf16
    short* UtB   = Ub + (size_t)J_DIM * D_DIM;     // D*J bf16

    hipLaunchKernelGGL(prep_kernel, dim3(J_DIM), dim3(128), 0, stream, U, Ws, uw2, Ub, UtB);
    hipLaunchKernelGGL(attn_kernel, dim3(T_ROWS / 16), dim3(256), 0, stream,
                       H, Ws, uw2, Ub, UtB, rstat, out);
    hipLaunchKernelGGL(bsoft_kernel, dim3(1), dim3(1024), 0, stream, rstat, bvec);
    hipLaunchKernelGGL(htilde_partial, dim3(256), dim3(512), 0, stream, H, bvec, part);
    hipLaunchKernelGGL(htilde_reduce, dim3(1), dim3(512), 0, stream, part, htld);
    hipLaunchKernelGGL(assemble_kernel, dim3(T_ROWS), dim3(128), 0, stream, H, htld, out);
}

// Round 2
// 264.292 us; speedup vs baseline: 1.2296x; 1.2296x over previous
//
#include <hip/hip_runtime.h>
#include <hip/hip_bf16.h>

#define T_ROWS 16384
#define J_DIM  1024
#define D_DIM  512

typedef __attribute__((ext_vector_type(8))) short bf16x8;
typedef __attribute__((ext_vector_type(4))) float f32x4;
typedef unsigned short u16;

__device__ inline u16 f2bf(float f) {
    union { float f; unsigned int u; } v; v.f = f;
    return (u16)((v.u + 0x7FFFu + ((v.u >> 16) & 1u)) >> 16);  // RNE
}

// ---------------------------------------------------------------------------
// prep_u: per U row j: uw2[j] = U_j.w2 ; scatter bf16(U) into fragment-major
//   Ubp  (S-GEMM B):  [(jt*16+ks)*64 + lane]*8 + e   (jt=j>>4, ks=k>>5)
//   Utp  (PV-GEMM B): [(dt*32+ks)*64 + lane]*8 + e   (dt=d>>4, ks=j>>5)
// ---------------------------------------------------------------------------
__global__ __launch_bounds__(128) void prep_u(
    const float* __restrict__ U, const float* __restrict__ Ws,
    float* __restrict__ uw2, u16* __restrict__ Ubp, u16* __restrict__ Utp)
{
    const int j = blockIdx.x;
    const int t = threadIdx.x;               // covers d/k = 4t..4t+3
    const float4 u  = ((const float4*)(U + (size_t)j * D_DIM))[t];
    const float4 w2 = ((const float4*)(Ws + D_DIM))[t];
    float p = u.x * w2.x + u.y * w2.y + u.z * w2.z + u.w * w2.w;
    #pragma unroll
    for (int m = 1; m < 64; m <<= 1) p += __shfl_xor(p, m);
    __shared__ float red[2];
    if ((t & 63) == 0) red[t >> 6] = p;
    __syncthreads();
    if (t == 0) uw2[j] = red[0] + red[1];

    u16 b0 = f2bf(u.x), b1 = f2bf(u.y), b2 = f2bf(u.z), b3 = f2bf(u.w);

    // Ubp: (j, k=4t..4t+3): ks=k>>5, quad=(k>>3)&3, e=k&7 (e0 in {0,4})
    {
        const int k0 = 4 * t;
        const size_t idx = (((size_t)(j >> 4) * 16 + (k0 >> 5)) * 64
                            + (((k0 >> 3) & 3) * 16 + (j & 15))) * 8 + (k0 & 7);
        ushort4 v; v.x = b0; v.y = b1; v.z = b2; v.w = b3;
        *(ushort4*)(Ubp + idx) = v;
    }
    // Utp: value U[j][d] -> (dt=d>>4, ks=j>>5, lane=((j>>3)&3)*16+(d&15), e=j&7)
    {
        const size_t jpart = ((size_t)(j >> 5)) * 64 * 8
                           + (size_t)(((j >> 3) & 3) * 16) * 8 + (j & 7);
        const u16 bs[4] = { b0, b1, b2, b3 };
        #pragma unroll
        for (int s = 0; s < 4; ++s) {
            const int d = 4 * t + s;
            Utp[((size_t)(d >> 4) * 32) * 512 + jpart + (size_t)(d & 15) * 8] = bs[s];
        }
    }
}

// ---------------------------------------------------------------------------
// prep_h: per H row i: hw1[i] = H_i.w1 ; Hq = bf16(H_i * w3) into out
//         cols[1024:1280) (ushort offset 2048 within the 4096-ushort row)
// ---------------------------------------------------------------------------
__global__ __launch_bounds__(128) void prep_h(
    const float* __restrict__ H, const float* __restrict__ Ws,
    float* __restrict__ hw1, u16* outU)
{
    const int i = blockIdx.x;
    const int t = threadIdx.x;
    const float4 h  = ((const float4*)(H + (size_t)i * D_DIM))[t];
    const float4 w1 = ((const float4*)Ws)[t];
    const float4 w3 = ((const float4*)(Ws + 2 * D_DIM))[t];
    float p = h.x * w1.x + h.y * w1.y + h.z * w1.z + h.w * w1.w;
    #pragma unroll
    for (int m = 1; m < 64; m <<= 1) p += __shfl_xor(p, m);
    __shared__ float red[2];
    if ((t & 63) == 0) red[t >> 6] = p;
    __syncthreads();
    if (t == 0) hw1[i] = red[0] + red[1];

    ushort4 q;
    q.x = f2bf(h.x * w3.x); q.y = f2bf(h.y * w3.y);
    q.z = f2bf(h.z * w3.z); q.w = f2bf(h.w * w3.w);
    *(ushort4*)(outU + (size_t)i * 4096 + 2048 + 4 * t) = q;
}

// ---------------------------------------------------------------------------
// s_kernel: S = Hq @ Ubp^T + uw2 -> row softmax (register-resident) ->
//           P bf16 into out cols[512:1024) ; rstat[i] = hw1[i] + rowmax
//   Block = 16 rows, 4 waves; wave w owns j in [w*256, w*256+256).
// ---------------------------------------------------------------------------
__global__ __launch_bounds__(256) void s_kernel(
    const u16* __restrict__ Ubp, const float* __restrict__ uw2,
    const float* __restrict__ hw1, float* __restrict__ rstat, u16* outU)
{
    const int tid  = threadIdx.x;
    const int w    = tid >> 6;
    const int lane = tid & 63;
    const int fr   = lane & 15;
    const int quad = lane >> 4;
    const int ib   = blockIdx.x * 16;
    const int j0   = w * 256;

    float u2[16];
    #pragma unroll
    for (int t = 0; t < 16; ++t) u2[t] = uw2[j0 + t * 16 + fr];

    f32x4 acc[16];
    #pragma unroll
    for (int t = 0; t < 16; ++t) acc[t] = (f32x4){0.f, 0.f, 0.f, 0.f};

    const u16* aPtr = outU + (size_t)(ib + fr) * 4096 + 2048 + quad * 8;
    const u16* bPtr = Ubp + (size_t)w * 131072 + (size_t)lane * 8;

    #pragma unroll
    for (int ks = 0; ks < 16; ++ks) {
        const bf16x8 qa = *(const bf16x8*)(aPtr + ks * 32);
        #pragma unroll
        for (int t = 0; t < 16; ++t) {
            const bf16x8 bb = *(const bf16x8*)(bPtr + (size_t)(t * 16 + ks) * 512);
            acc[t] = __builtin_amdgcn_mfma_f32_16x16x32_bf16(qa, bb, acc[t], 0, 0, 0);
        }
    }

    // add uw2, row max (row = quad*4+m, cols t*16+fr across 16 lanes)
    float mx[4];
    #pragma unroll
    for (int m = 0; m < 4; ++m) {
        float v = -1e30f;
        #pragma unroll
        for (int t = 0; t < 16; ++t) { acc[t][m] += u2[t]; v = fmaxf(v, acc[t][m]); }
        v = fmaxf(v, __shfl_xor(v, 1));
        v = fmaxf(v, __shfl_xor(v, 2));
        v = fmaxf(v, __shfl_xor(v, 4));
        v = fmaxf(v, __shfl_xor(v, 8));
        mx[m] = v;
    }
    __shared__ float redM[4][16];
    __shared__ float redS[4][16];
    if (fr == 0) {
        #pragma unroll
        for (int m = 0; m < 4; ++m) redM[w][quad * 4 + m] = mx[m];
    }
    __syncthreads();
    float gm[4];
    #pragma unroll
    for (int m = 0; m < 4; ++m) {
        const int r = quad * 4 + m;
        gm[m] = fmaxf(fmaxf(redM[0][r], redM[1][r]), fmaxf(redM[2][r], redM[3][r]));
    }
    float sm[4] = {0.f, 0.f, 0.f, 0.f};
    #pragma unroll
    for (int t = 0; t < 16; ++t)
        #pragma unroll
        for (int m = 0; m < 4; ++m) {
            const float e = __expf(acc[t][m] - gm[m]);
            acc[t][m] = e;
            sm[m] += e;
        }
    #pragma unroll
    for (int m = 0; m < 4; ++m) {
        sm[m] += __shfl_xor(sm[m], 1);
        sm[m] += __shfl_xor(sm[m], 2);
        sm[m] += __shfl_xor(sm[m], 4);
        sm[m] += __shfl_xor(sm[m], 8);
    }
    if (fr == 0) {
        #pragma unroll
        for (int m = 0; m < 4; ++m) redS[w][quad * 4 + m] = sm[m];
    }
    __syncthreads();
    float inv[4];
    #pragma unroll
    for (int m = 0; m < 4; ++m) {
        const int r = quad * 4 + m;
        inv[m] = 1.f / (redS[0][r] + redS[1][r] + redS[2][r] + redS[3][r]);
    }
    if (w == 0 && fr == 0) {
        #pragma unroll
        for (int m = 0; m < 4; ++m)
            rstat[ib + quad * 4 + m] = gm[m] + hw1[ib + quad * 4 + m];
    }
    #pragma unroll
    for (int t = 0; t < 16; ++t)
        #pragma unroll
        for (int m = 0; m < 4; ++m)
            outU[(size_t)(ib + quad * 4 + m) * 4096 + 1024 + j0 + t * 16 + fr] =
                f2bf(acc[t][m] * inv[m]);
}

// ---------------------------------------------------------------------------
// bsoft: b = softmax(rstat) over 16384 (single block)
// ---------------------------------------------------------------------------
__global__ __launch_bounds__(1024) void bsoft_kernel(
    const float* __restrict__ r, float* __restrict__ b)
{
    __shared__ float red[16];
    __shared__ float Msh, Lsh;
    const int t = threadIdx.x;
    float m = -1e30f;
    #pragma unroll
    for (int e = 0; e < 16; ++e) m = fmaxf(m, r[t + e * 1024]);
    #pragma unroll
    for (int s = 1; s < 64; s <<= 1) m = fmaxf(m, __shfl_xor(m, s));
    if ((t & 63) == 0) red[t >> 6] = m;
    __syncthreads();
    if (t == 0) {
        float M = red[0];
        for (int i = 1; i < 16; ++i) M = fmaxf(M, red[i]);
        Msh = M;
    }
    __syncthreads();
    const float M = Msh;
    float l = 0.f;
    #pragma unroll
    for (int e = 0; e < 16; ++e) l += __expf(r[t + e * 1024] - M);
    #pragma unroll
    for (int s = 1; s < 64; s <<= 1) l += __shfl_xor(l, s);
    if ((t & 63) == 0) red[t >> 6] = l;
    __syncthreads();
    if (t == 0) {
        float L = 0.f;
        for (int i = 0; i < 16; ++i) L += red[i];
        Lsh = L;
    }
    __syncthreads();
    const float invL = 1.f / Lsh;
    #pragma unroll
    for (int e = 0; e < 16; ++e) b[t + e * 1024] = __expf(r[t + e * 1024] - M) * invL;
}

// ---------------------------------------------------------------------------
// h_tilde = b @ H (two-stage deterministic)
// ---------------------------------------------------------------------------
__global__ __launch_bounds__(512) void htilde_partial(
    const float* __restrict__ H, const float* __restrict__ b,
    float* __restrict__ part)
{
    const int blk = blockIdx.x;
    const int d = threadIdx.x;
    const int i0 = blk * 64;
    float s = 0.f;
    for (int rI = 0; rI < 64; ++rI)
        s += b[i0 + rI] * H[(size_t)(i0 + rI) * D_DIM + d];
    part[(size_t)blk * D_DIM + d] = s;
}

__global__ __launch_bounds__(512) void htilde_reduce(
    const float* __restrict__ part, float* __restrict__ ht)
{
    const int d = threadIdx.x;
    float s = 0.f;
    for (int p = 0; p < 256; ++p) s += part[(size_t)p * D_DIM + d];
    ht[d] = s;
}

// ---------------------------------------------------------------------------
// pv_kernel: AQ = P @ U (P bf16 from out cols[512:1024)) + fused G assembly.
//   Block = 16 rows, 4 waves; wave w owns d in [w*128, w*128+128).
// ---------------------------------------------------------------------------
__global__ __launch_bounds__(256) void pv_kernel(
    const u16* __restrict__ Utp, const float* __restrict__ H,
    const float* __restrict__ htld, float* out)
{
    const int tid  = threadIdx.x;
    const int w    = tid >> 6;
    const int lane = tid & 63;
    const int fr   = lane & 15;
    const int quad = lane >> 4;
    const int ib   = blockIdx.x * 16;

    const u16* outU = (const u16*)out;
    f32x4 acc[8];
    #pragma unroll
    for (int i = 0; i < 8; ++i) acc[i] = (f32x4){0.f, 0.f, 0.f, 0.f};

    const u16* aPtr = outU + (size_t)(ib + fr) * 4096 + 1024 + quad * 8;
    const u16* bPtr = Utp + (size_t)w * 131072 + (size_t)lane * 8;

    #pragma unroll 8
    for (int ks = 0; ks < 32; ++ks) {
        const bf16x8 pa = *(const bf16x8*)(aPtr + ks * 32);
        #pragma unroll
        for (int i = 0; i < 8; ++i) {
            const bf16x8 bb = *(const bf16x8*)(bPtr + (size_t)(i * 32 + ks) * 512);
            acc[i] = __builtin_amdgcn_mfma_f32_16x16x32_bf16(pa, bb, acc[i], 0, 0, 0);
        }
    }
    __syncthreads();   // all P reads done before AQ overwrites cols[512:1024)

    float hld[8];
    #pragma unroll
    for (int i = 0; i < 8; ++i) hld[i] = htld[w * 128 + i * 16 + fr];

    #pragma unroll
    for (int m = 0; m < 4; ++m) {
        const int r = ib + quad * 4 + m;
        const float* hrow = H + (size_t)r * D_DIM;
        float* obase = out + (size_t)r * 2048;
        #pragma unroll
        for (int i = 0; i < 8; ++i) {
            const int c = w * 128 + i * 16 + fr;
            const float h  = hrow[c];
            const float aq = acc[i][m];
            obase[c]        = h;
            obase[512 + c]  = aq;
            obase[1024 + c] = h * aq;
            obase[1536 + c] = h * hld[i];
        }
    }
}

// ---------------------------------------------------------------------------
extern "C" void kernel_launch(void* const* d_in, const int* in_sizes, int n_in,
                              void* d_out, int out_size, void* d_ws, size_t ws_size,
                              hipStream_t stream)
{
    const float* H  = (const float*)d_in[0];
    const float* U  = (const float*)d_in[1];
    const float* Ws = (const float*)d_in[2];
    float* out = (float*)d_out;
    u16* outU = (u16*)d_out;

    float* uw2   = (float*)d_ws;                   // 1024
    float* rstat = uw2 + 1024;                     // 16384
    float* bvec  = rstat + T_ROWS;                 // 16384
    float* hw1   = bvec + T_ROWS;                  // 16384
    float* htld  = hw1 + T_ROWS;                   // 512
    float* part  = htld + D_DIM;                   // 256*512
    u16*   Ubp   = (u16*)(part + 256 * D_DIM);     // 512K u16 (1 MB)
    u16*   Utp   = Ubp + 524288;                   // 512K u16 (1 MB)

    hipLaunchKernelGGL(prep_u, dim3(J_DIM), dim3(128), 0, stream, U, Ws, uw2, Ubp, Utp);
    hipLaunchKernelGGL(prep_h, dim3(T_ROWS), dim3(128), 0, stream, H, Ws, hw1, outU);
    hipLaunchKernelGGL(s_kernel, dim3(T_ROWS / 16), dim3(256), 0, stream,
                       Ubp, uw2, hw1, rstat, outU);
    hipLaunchKernelGGL(bsoft_kernel, dim3(1), dim3(1024), 0, stream, rstat, bvec);
    hipLaunchKernelGGL(htilde_partial, dim3(256), dim3(512), 0, stream, H, bvec, part);
    hipLaunchKernelGGL(htilde_reduce, dim3(1), dim3(512), 0, stream, part, htld);
    hipLaunchKernelGGL(pv_kernel, dim3(T_ROWS / 16), dim3(256), 0, stream,
                       Utp, H, htld, out);
}

// Round 3
// 132.091 us; speedup vs baseline: 2.4603x; 2.0008x over previous
//
#include <hip/hip_runtime.h>
#include <hip/hip_bf16.h>

#define T_ROWS 16384
#define J_DIM  1024
#define D_DIM  512

typedef __attribute__((ext_vector_type(8))) short bf16x8;
typedef __attribute__((ext_vector_type(4))) float f32x4;
typedef unsigned short u16;

__device__ __forceinline__ u16 f2bf(float f) {
    union { float f; unsigned int u; } v; v.f = f;
    return (u16)((v.u + 0x7FFFu + ((v.u >> 16) & 1u)) >> 16);  // RNE
}

// async global->LDS, 16B per lane. LDS dest must be wave-uniform base + lane*16.
__device__ __forceinline__ void gload16(const void* g, void* l) {
    __builtin_amdgcn_global_load_lds(
        (__attribute__((address_space(1))) void*)(unsigned long long)(size_t)g,
        (__attribute__((address_space(3))) void*)(unsigned int)(size_t)l,
        16, 0, 0);
}

// ---------------------------------------------------------------------------
// m97-style 128x128 tile GEMM core, BK=32, bf16 MFMA 16x16x32.
// A: [128 rows][lda] bf16 K-contiguous; B: [128 rows][ldb] bf16 K-contiguous.
// LDS tiles [128][32] u16, 16B-slot XOR swizzle: slot' = slot ^ ((row>>1)&3),
// applied on the GLOBAL source (gload_lds writes linearly) and on ds_read.
// ---------------------------------------------------------------------------
template<int NT>
__device__ __forceinline__ void gemm_core(
    const u16* A, int lda, const u16* B, int ldb, u16* lds, f32x4 (&acc)[4][4])
{
    const int tid  = threadIdx.x;
    const int lane = tid & 63;
    const int w    = tid >> 6;
    const int wr   = w >> 1, wc = w & 1;
    const int fr   = lane & 15, quad = lane >> 4;

    const int srow = tid >> 2;                       // 0..63 (plus +64 second call)
    const int ss   = (tid & 3) ^ ((srow >> 1) & 3);  // swizzled source 16B-slot

    const u16* gA0 = A + (size_t)srow * lda + ss * 8;
    const u16* gA1 = A + (size_t)(srow + 64) * lda + ss * 8;
    const u16* gB0 = B + (size_t)srow * ldb + ss * 8;
    const u16* gB1 = B + (size_t)(srow + 64) * ldb + ss * 8;

    u16* As = lds;            // [2][4096]
    u16* Bs = lds + 8192;     // [2][4096]
    u16* dA0 = As + tid * 8;
    u16* dA1 = As + 2048 + tid * 8;
    u16* dB0 = Bs + tid * 8;
    u16* dB1 = Bs + 2048 + tid * 8;

    gload16(gA0, dA0); gload16(gA1, dA1);
    gload16(gB0, dB0); gload16(gB1, dB1);
    gA0 += 32; gA1 += 32; gB0 += 32; gB1 += 32;

    int offA[4], offB[4];
    #pragma unroll
    for (int i = 0; i < 4; ++i) {
        const int rA = wr * 64 + i * 16 + fr;
        offA[i] = rA * 32 + (quad ^ ((rA >> 1) & 3)) * 8;
        const int rB = wc * 64 + i * 16 + fr;
        offB[i] = rB * 32 + (quad ^ ((rB >> 1) & 3)) * 8;
    }
    __syncthreads();   // drains vmcnt: buf0 staged

    #pragma unroll 2
    for (int t = 0; t < NT; ++t) {
        const int cur = (t & 1) * 4096;
        const int nxt = 4096 - cur;
        if (t + 1 < NT) {
            gload16(gA0, dA0 + nxt); gload16(gA1, dA1 + nxt);
            gload16(gB0, dB0 + nxt); gload16(gB1, dB1 + nxt);
            gA0 += 32; gA1 += 32; gB0 += 32; gB1 += 32;
        }
        const u16* Ac = As + cur;
        const u16* Bc = Bs + cur;
        bf16x8 af[4], bfr[4];
        #pragma unroll
        for (int i = 0; i < 4; ++i) af[i]  = *(const bf16x8*)(Ac + offA[i]);
        #pragma unroll
        for (int i = 0; i < 4; ++i) bfr[i] = *(const bf16x8*)(Bc + offB[i]);
        #pragma unroll
        for (int mf = 0; mf < 4; ++mf)
            #pragma unroll
            for (int nf = 0; nf < 4; ++nf)
                acc[mf][nf] = __builtin_amdgcn_mfma_f32_16x16x32_bf16(
                    af[mf], bfr[nf], acc[mf][nf], 0, 0, 0);
        __syncthreads();  // drains vmcnt (next buf staged) + protects buffer reuse
    }
}

// ---------------------------------------------------------------------------
// prep_u: uw2[j] = U_j.w2 ; Ub[j][k] = bf16(U) ; Ut[d][j] = bf16(U^T)
// ---------------------------------------------------------------------------
__global__ __launch_bounds__(128) void prep_u(
    const float* __restrict__ U, const float* __restrict__ Ws,
    float* __restrict__ uw2, u16* __restrict__ Ub, u16* __restrict__ Ut)
{
    const int j = blockIdx.x;
    const int t = threadIdx.x;
    const float4 u  = ((const float4*)(U + (size_t)j * D_DIM))[t];
    const float4 w2 = ((const float4*)(Ws + D_DIM))[t];
    float p = u.x * w2.x + u.y * w2.y + u.z * w2.z + u.w * w2.w;
    #pragma unroll
    for (int m = 1; m < 64; m <<= 1) p += __shfl_xor(p, m);
    __shared__ float red[2];
    if ((t & 63) == 0) red[t >> 6] = p;
    __syncthreads();
    if (t == 0) uw2[j] = red[0] + red[1];

    ushort4 v;
    v.x = f2bf(u.x); v.y = f2bf(u.y); v.z = f2bf(u.z); v.w = f2bf(u.w);
    ((ushort4*)(Ub + (size_t)j * D_DIM))[t] = v;
    const u16 bs[4] = { v.x, v.y, v.z, v.w };
    #pragma unroll
    for (int s = 0; s < 4; ++s)
        Ut[(size_t)(4 * t + s) * J_DIM + j] = bs[s];
}

// ---------------------------------------------------------------------------
// prep_h: hw1[i] = H_i.w1 ; Hq = bf16(H_i*w3) -> out u16 cols [3072:3584)
// ---------------------------------------------------------------------------
__global__ __launch_bounds__(128) void prep_h(
    const float* __restrict__ H, const float* __restrict__ Ws,
    float* __restrict__ hw1, u16* outU)
{
    const int i = blockIdx.x;
    const int t = threadIdx.x;
    const float4 h  = ((const float4*)(H + (size_t)i * D_DIM))[t];
    const float4 w1 = ((const float4*)Ws)[t];
    const float4 w3 = ((const float4*)(Ws + 2 * D_DIM))[t];
    float p = h.x * w1.x + h.y * w1.y + h.z * w1.z + h.w * w1.w;
    #pragma unroll
    for (int m = 1; m < 64; m <<= 1) p += __shfl_xor(p, m);
    __shared__ float red[2];
    if ((t & 63) == 0) red[t >> 6] = p;
    __syncthreads();
    if (t == 0) hw1[i] = red[0] + red[1];

    ushort4 q;
    q.x = f2bf(h.x * w3.x); q.y = f2bf(h.y * w3.y);
    q.z = f2bf(h.z * w3.z); q.w = f2bf(h.w * w3.w);
    *(ushort4*)(outU + (size_t)i * 4096 + 3072 + 4 * t) = q;
}

// ---------------------------------------------------------------------------
// s_gemm: S = Hq @ Ub^T + uw2 -> out f32 cols [0:1024)
// ---------------------------------------------------------------------------
__global__ __launch_bounds__(256) void s_gemm(
    u16* outU, const u16* __restrict__ Ub, const float* __restrict__ uw2)
{
    __shared__ u16 lds[16384];
    const int bid = blockIdx.x;                       // 1024
    const int swz = (bid & 7) * 128 + (bid >> 3);     // XCD swizzle (bijective)
    const int bm = swz >> 3, nb = swz & 7;            // nb fast: A-panel reuse

    f32x4 acc[4][4];
    #pragma unroll
    for (int i = 0; i < 4; ++i)
        #pragma unroll
        for (int j = 0; j < 4; ++j) acc[i][j] = (f32x4){0.f, 0.f, 0.f, 0.f};

    gemm_core<16>(outU + (size_t)bm * 128 * 4096 + 3072, 4096,
                  Ub + (size_t)nb * 128 * 512, 512, lds, acc);

    const int tid = threadIdx.x, lane = tid & 63, w = tid >> 6;
    const int wr = w >> 1, wc = w & 1, fr = lane & 15, quad = lane >> 4;
    float* outF = (float*)outU;
    int jc[4]; float u2[4];
    #pragma unroll
    for (int nf = 0; nf < 4; ++nf) {
        jc[nf] = nb * 128 + wc * 64 + nf * 16 + fr;
        u2[nf] = uw2[jc[nf]];
    }
    #pragma unroll
    for (int mf = 0; mf < 4; ++mf)
        #pragma unroll
        for (int m = 0; m < 4; ++m) {
            const size_t row = bm * 128 + wr * 64 + mf * 16 + quad * 4 + m;
            float* rp = outF + row * 2048;
            #pragma unroll
            for (int nf = 0; nf < 4; ++nf) rp[jc[nf]] = acc[mf][nf][m] + u2[nf];
        }
}

// ---------------------------------------------------------------------------
// softmax: wave per row; read S f32 cols [0:1024), write P bf16 u16 [1024:2048)
// rstat[i] = rowmax + hw1[i]
// ---------------------------------------------------------------------------
__global__ __launch_bounds__(256) void softmax_kernel(
    u16* outU, const float* __restrict__ hw1, float* __restrict__ rstat)
{
    const int lane = threadIdx.x & 63;
    const int w = threadIdx.x >> 6;
    const size_t row = (size_t)blockIdx.x * 4 + w;
    float* outF = (float*)outU;
    float4 v[4];
    #pragma unroll
    for (int e = 0; e < 4; ++e)
        v[e] = *(const float4*)(outF + row * 2048 + e * 256 + lane * 4);
    float mx = -1e30f;
    #pragma unroll
    for (int e = 0; e < 4; ++e)
        mx = fmaxf(mx, fmaxf(fmaxf(v[e].x, v[e].y), fmaxf(v[e].z, v[e].w)));
    #pragma unroll
    for (int s = 1; s < 64; s <<= 1) mx = fmaxf(mx, __shfl_xor(mx, s));
    float sum = 0.f;
    #pragma unroll
    for (int e = 0; e < 4; ++e) {
        v[e].x = __expf(v[e].x - mx); v[e].y = __expf(v[e].y - mx);
        v[e].z = __expf(v[e].z - mx); v[e].w = __expf(v[e].w - mx);
        sum += v[e].x + v[e].y + v[e].z + v[e].w;
    }
    #pragma unroll
    for (int s = 1; s < 64; s <<= 1) sum += __shfl_xor(sum, s);
    const float inv = 1.f / sum;
    #pragma unroll
    for (int e = 0; e < 4; ++e) {
        ushort4 p;
        p.x = f2bf(v[e].x * inv); p.y = f2bf(v[e].y * inv);
        p.z = f2bf(v[e].z * inv); p.w = f2bf(v[e].w * inv);
        *(ushort4*)(outU + row * 4096 + 1024 + e * 256 + lane * 4) = p;
    }
    if (lane == 0) rstat[row] = mx + hw1[row];
}

// ---------------------------------------------------------------------------
// bsoft: b = softmax(rstat) over 16384 (single block)
// ---------------------------------------------------------------------------
__global__ __launch_bounds__(1024) void bsoft_kernel(
    const float* __restrict__ r, float* __restrict__ b)
{
    __shared__ float red[16];
    __shared__ float Msh, Lsh;
    const int t = threadIdx.x;
    float m = -1e30f;
    #pragma unroll
    for (int e = 0; e < 16; ++e) m = fmaxf(m, r[t + e * 1024]);
    #pragma unroll
    for (int s = 1; s < 64; s <<= 1) m = fmaxf(m, __shfl_xor(m, s));
    if ((t & 63) == 0) red[t >> 6] = m;
    __syncthreads();
    if (t == 0) {
        float M = red[0];
        for (int i = 1; i < 16; ++i) M = fmaxf(M, red[i]);
        Msh = M;
    }
    __syncthreads();
    const float M = Msh;
    float l = 0.f;
    #pragma unroll
    for (int e = 0; e < 16; ++e) l += __expf(r[t + e * 1024] - M);
    #pragma unroll
    for (int s = 1; s < 64; s <<= 1) l += __shfl_xor(l, s);
    if ((t & 63) == 0) red[t >> 6] = l;
    __syncthreads();
    if (t == 0) {
        float L = 0.f;
        for (int i = 0; i < 16; ++i) L += red[i];
        Lsh = L;
    }
    __syncthreads();
    const float invL = 1.f / Lsh;
    #pragma unroll
    for (int e = 0; e < 16; ++e) b[t + e * 1024] = __expf(r[t + e * 1024] - M) * invL;
}

// ---------------------------------------------------------------------------
// h_tilde = b @ H (two-stage deterministic)
// ---------------------------------------------------------------------------
__global__ __launch_bounds__(512) void htilde_partial(
    const float* __restrict__ H, const float* __restrict__ b,
    float* __restrict__ part)
{
    const int blk = blockIdx.x;
    const int d = threadIdx.x;
    const int i0 = blk * 64;
    float s = 0.f;
    for (int rI = 0; rI < 64; ++rI)
        s += b[i0 + rI] * H[(size_t)(i0 + rI) * D_DIM + d];
    part[(size_t)blk * D_DIM + d] = s;
}

__global__ __launch_bounds__(512) void htilde_reduce(
    const float* __restrict__ part, float* __restrict__ ht)
{
    const int d = threadIdx.x;
    float s = 0.f;
    for (int p = 0; p < 256; ++p) s += part[(size_t)p * D_DIM + d];
    ht[d] = s;
}

// ---------------------------------------------------------------------------
// pv_gemm: AQ = P @ Ut^T, fused G assembly epilogue.
// ---------------------------------------------------------------------------
__global__ __launch_bounds__(256) void pv_gemm(
    u16* outU, const u16* __restrict__ Ut, const float* __restrict__ H,
    const float* __restrict__ htld)
{
    __shared__ u16 lds[16384];
    const int bid = blockIdx.x;                      // 512
    const int swz = (bid & 7) * 64 + (bid >> 3);
    const int bm = swz >> 2, nb = swz & 3;

    f32x4 acc[4][4];
    #pragma unroll
    for (int i = 0; i < 4; ++i)
        #pragma unroll
        for (int j = 0; j < 4; ++j) acc[i][j] = (f32x4){0.f, 0.f, 0.f, 0.f};

    gemm_core<32>(outU + (size_t)bm * 128 * 4096 + 1024, 4096,
                  Ut + (size_t)nb * 128 * 1024, 1024, lds, acc);

    const int tid = threadIdx.x, lane = tid & 63, w = tid >> 6;
    const int wr = w >> 1, wc = w & 1, fr = lane & 15, quad = lane >> 4;
    float* outF = (float*)outU;
    int c[4]; float ht[4];
    #pragma unroll
    for (int nf = 0; nf < 4; ++nf) {
        c[nf] = nb * 128 + wc * 64 + nf * 16 + fr;
        ht[nf] = htld[c[nf]];
    }
    #pragma unroll
    for (int mf = 0; mf < 4; ++mf)
        #pragma unroll
        for (int m = 0; m < 4; ++m) {
            const size_t row = bm * 128 + wr * 64 + mf * 16 + quad * 4 + m;
            const float* hrow = H + row * D_DIM;
            float* ob = outF + row * 2048;
            #pragma unroll
            for (int nf = 0; nf < 4; ++nf) {
                const float h  = hrow[c[nf]];
                const float aq = acc[mf][nf][m];
                ob[c[nf]]        = h;
                ob[512 + c[nf]]  = aq;
                ob[1024 + c[nf]] = h * aq;
                ob[1536 + c[nf]] = h * ht[nf];
            }
        }
}

// ---------------------------------------------------------------------------
extern "C" void kernel_launch(void* const* d_in, const int* in_sizes, int n_in,
                              void* d_out, int out_size, void* d_ws, size_t ws_size,
                              hipStream_t stream)
{
    const float* H  = (const float*)d_in[0];
    const float* U  = (const float*)d_in[1];
    const float* Ws = (const float*)d_in[2];
    u16* outU = (u16*)d_out;

    float* uw2   = (float*)d_ws;                   // 1024
    float* rstat = uw2 + 1024;                     // 16384
    float* bvec  = rstat + T_ROWS;                 // 16384
    float* hw1   = bvec + T_ROWS;                  // 16384
    float* htld  = hw1 + T_ROWS;                   // 512
    float* part  = htld + D_DIM;                   // 256*512
    u16*   Ub    = (u16*)(part + 256 * D_DIM);     // 1 MB
    u16*   Ut    = Ub + (size_t)J_DIM * D_DIM;     // 1 MB

    hipLaunchKernelGGL(prep_u, dim3(J_DIM), dim3(128), 0, stream, U, Ws, uw2, Ub, Ut);
    hipLaunchKernelGGL(prep_h, dim3(T_ROWS), dim3(128), 0, stream, H, Ws, hw1, outU);
    hipLaunchKernelGGL(s_gemm, dim3(1024), dim3(256), 0, stream, outU, Ub, uw2);
    hipLaunchKernelGGL(softmax_kernel, dim3(T_ROWS / 4), dim3(256), 0, stream,
                       outU, hw1, rstat);
    hipLaunchKernelGGL(bsoft_kernel, dim3(1), dim3(1024), 0, stream, rstat, bvec);
    hipLaunchKernelGGL(htilde_partial, dim3(256), dim3(512), 0, stream, H, bvec, part);
    hipLaunchKernelGGL(htilde_reduce, dim3(1), dim3(512), 0, stream, part, htld);
    hipLaunchKernelGGL(pv_gemm, dim3(512), dim3(256), 0, stream, outU, Ut, H, htld);
}

// Round 4
// 130.810 us; speedup vs baseline: 2.4843x; 1.0098x over previous
//
#include <hip/hip_runtime.h>
#include <hip/hip_bf16.h>

#define T_ROWS 16384
#define J_DIM  1024
#define D_DIM  512

typedef __attribute__((ext_vector_type(8))) short bf16x8;
typedef __attribute__((ext_vector_type(4))) float f32x4;
typedef unsigned short u16;

__device__ __forceinline__ u16 f2bf(float f) {
    union { float f; unsigned int u; } v; v.f = f;
    return (u16)((v.u + 0x7FFFu + ((v.u >> 16) & 1u)) >> 16);  // RNE
}
__device__ __forceinline__ float bf2f(u16 b) {
    union { unsigned int u; float f; } v; v.u = ((unsigned int)b) << 16;
    return v.f;
}

// async global->LDS, 16B per lane. LDS dest must be wave-uniform base + lane*16.
__device__ __forceinline__ void gload16(const void* g, void* l) {
    __builtin_amdgcn_global_load_lds(
        (__attribute__((address_space(1))) void*)(unsigned long long)(size_t)g,
        (__attribute__((address_space(3))) void*)(unsigned int)(size_t)l,
        16, 0, 0);
}

// ---------------------------------------------------------------------------
// m97-style 128x128 tile GEMM core, BK=32, bf16 MFMA 16x16x32 (round-3, kept).
// ---------------------------------------------------------------------------
template<int NT>
__device__ __forceinline__ void gemm_core(
    const u16* A, int lda, const u16* B, int ldb, u16* lds, f32x4 (&acc)[4][4])
{
    const int tid  = threadIdx.x;
    const int lane = tid & 63;
    const int w    = tid >> 6;
    const int wr   = w >> 1, wc = w & 1;
    const int fr   = lane & 15, quad = lane >> 4;

    const int srow = tid >> 2;
    const int ss   = (tid & 3) ^ ((srow >> 1) & 3);

    const u16* gA0 = A + (size_t)srow * lda + ss * 8;
    const u16* gA1 = A + (size_t)(srow + 64) * lda + ss * 8;
    const u16* gB0 = B + (size_t)srow * ldb + ss * 8;
    const u16* gB1 = B + (size_t)(srow + 64) * ldb + ss * 8;

    u16* As = lds;            // [2][4096]
    u16* Bs = lds + 8192;     // [2][4096]
    u16* dA0 = As + tid * 8;
    u16* dA1 = As + 2048 + tid * 8;
    u16* dB0 = Bs + tid * 8;
    u16* dB1 = Bs + 2048 + tid * 8;

    gload16(gA0, dA0); gload16(gA1, dA1);
    gload16(gB0, dB0); gload16(gB1, dB1);
    gA0 += 32; gA1 += 32; gB0 += 32; gB1 += 32;

    int offA[4], offB[4];
    #pragma unroll
    for (int i = 0; i < 4; ++i) {
        const int rA = wr * 64 + i * 16 + fr;
        offA[i] = rA * 32 + (quad ^ ((rA >> 1) & 3)) * 8;
        const int rB = wc * 64 + i * 16 + fr;
        offB[i] = rB * 32 + (quad ^ ((rB >> 1) & 3)) * 8;
    }
    __syncthreads();

    #pragma unroll 2
    for (int t = 0; t < NT; ++t) {
        const int cur = (t & 1) * 4096;
        const int nxt = 4096 - cur;
        if (t + 1 < NT) {
            gload16(gA0, dA0 + nxt); gload16(gA1, dA1 + nxt);
            gload16(gB0, dB0 + nxt); gload16(gB1, dB1 + nxt);
            gA0 += 32; gA1 += 32; gB0 += 32; gB1 += 32;
        }
        const u16* Ac = As + cur;
        const u16* Bc = Bs + cur;
        bf16x8 af[4], bfr[4];
        #pragma unroll
        for (int i = 0; i < 4; ++i) af[i]  = *(const bf16x8*)(Ac + offA[i]);
        #pragma unroll
        for (int i = 0; i < 4; ++i) bfr[i] = *(const bf16x8*)(Bc + offB[i]);
        #pragma unroll
        for (int mf = 0; mf < 4; ++mf)
            #pragma unroll
            for (int nf = 0; nf < 4; ++nf)
                acc[mf][nf] = __builtin_amdgcn_mfma_f32_16x16x32_bf16(
                    af[mf], bfr[nf], acc[mf][nf], 0, 0, 0);
        __syncthreads();
    }
}

// ---------------------------------------------------------------------------
// prep_u: uw2[j]=U_j.w2 ; Ub row-major bf16 (s_gemm B); Utp fragment-major
// (pv B): value U[j][d] -> Utp[(d>>4)*16384 + (j>>5)*512 + ((j>>3)&3)*128
//                               + (d&15)*8 + (j&7)]
// ---------------------------------------------------------------------------
__global__ __launch_bounds__(128) void prep_u(
    const float* __restrict__ U, const float* __restrict__ Ws,
    float* __restrict__ uw2, u16* __restrict__ Ub, u16* __restrict__ Utp)
{
    const int j = blockIdx.x;
    const int t = threadIdx.x;
    const float4 u  = ((const float4*)(U + (size_t)j * D_DIM))[t];
    const float4 w2 = ((const float4*)(Ws + D_DIM))[t];
    float p = u.x * w2.x + u.y * w2.y + u.z * w2.z + u.w * w2.w;
    #pragma unroll
    for (int m = 1; m < 64; m <<= 1) p += __shfl_xor(p, m);
    __shared__ float red[2];
    if ((t & 63) == 0) red[t >> 6] = p;
    __syncthreads();
    if (t == 0) uw2[j] = red[0] + red[1];

    ushort4 v;
    v.x = f2bf(u.x); v.y = f2bf(u.y); v.z = f2bf(u.z); v.w = f2bf(u.w);
    ((ushort4*)(Ub + (size_t)j * D_DIM))[t] = v;

    const size_t jpart = (size_t)(j >> 5) * 512 + (size_t)(((j >> 3) & 3) * 128) + (j & 7);
    const u16 bs[4] = { v.x, v.y, v.z, v.w };
    #pragma unroll
    for (int s = 0; s < 4; ++s) {
        const int d = 4 * t + s;
        Utp[(size_t)(d >> 4) * 16384 + jpart + (size_t)(d & 15) * 8] = bs[s];
    }
}

// ---------------------------------------------------------------------------
// prep_h: hw1[i] = H_i.w1 ; Hq = bf16(H_i*w3) -> out u16 cols [3072:3584)
// ---------------------------------------------------------------------------
__global__ __launch_bounds__(128) void prep_h(
    const float* __restrict__ H, const float* __restrict__ Ws,
    float* __restrict__ hw1, u16* outU)
{
    const int i = blockIdx.x;
    const int t = threadIdx.x;
    const float4 h  = ((const float4*)(H + (size_t)i * D_DIM))[t];
    const float4 w1 = ((const float4*)Ws)[t];
    const float4 w3 = ((const float4*)(Ws + 2 * D_DIM))[t];
    float p = h.x * w1.x + h.y * w1.y + h.z * w1.z + h.w * w1.w;
    #pragma unroll
    for (int m = 1; m < 64; m <<= 1) p += __shfl_xor(p, m);
    __shared__ float red[2];
    if ((t & 63) == 0) red[t >> 6] = p;
    __syncthreads();
    if (t == 0) hw1[i] = red[0] + red[1];

    ushort4 q;
    q.x = f2bf(h.x * w3.x); q.y = f2bf(h.y * w3.y);
    q.z = f2bf(h.z * w3.z); q.w = f2bf(h.w * w3.w);
    *(ushort4*)(outU + (size_t)i * 4096 + 3072 + 4 * t) = q;
}

// ---------------------------------------------------------------------------
// s_gemm: S = Hq @ Ub^T + uw2 -> bf16 into out u16 cols [1024:2048);
// pmax[row*8+nb] = local row max (f32, pre-quantization).
// ---------------------------------------------------------------------------
__global__ __launch_bounds__(256) void s_gemm(
    u16* outU, const u16* __restrict__ Ub, const float* __restrict__ uw2,
    float* __restrict__ pmax)
{
    __shared__ u16 lds[16384];
    const int bid = blockIdx.x;                       // 1024
    const int swz = (bid & 7) * 128 + (bid >> 3);     // XCD swizzle (bijective)
    const int bm = swz >> 3, nb = swz & 7;            // nb fast: A-panel reuse

    f32x4 acc[4][4];
    #pragma unroll
    for (int i = 0; i < 4; ++i)
        #pragma unroll
        for (int j = 0; j < 4; ++j) acc[i][j] = (f32x4){0.f, 0.f, 0.f, 0.f};

    gemm_core<16>(outU + (size_t)bm * 128 * 4096 + 3072, 4096,
                  Ub + (size_t)nb * 128 * 512, 512, lds, acc);

    const int tid = threadIdx.x, lane = tid & 63, w = tid >> 6;
    const int wr = w >> 1, wc = w & 1, fr = lane & 15, quad = lane >> 4;
    int jc[4]; float u2[4];
    #pragma unroll
    for (int nf = 0; nf < 4; ++nf) {
        jc[nf] = nb * 128 + wc * 64 + nf * 16 + fr;
        u2[nf] = uw2[jc[nf]];
    }
    float* redf = (float*)lds;   // 256 floats, staging done
    #pragma unroll
    for (int mf = 0; mf < 4; ++mf)
        #pragma unroll
        for (int m = 0; m < 4; ++m) {
            float mv = -1e30f;
            #pragma unroll
            for (int nf = 0; nf < 4; ++nf) {
                acc[mf][nf][m] += u2[nf];
                mv = fmaxf(mv, acc[mf][nf][m]);
            }
            mv = fmaxf(mv, __shfl_xor(mv, 1));
            mv = fmaxf(mv, __shfl_xor(mv, 2));
            mv = fmaxf(mv, __shfl_xor(mv, 4));
            mv = fmaxf(mv, __shfl_xor(mv, 8));
            if (fr == 0) redf[wc * 128 + wr * 64 + mf * 16 + quad * 4 + m] = mv;
        }
    __syncthreads();
    if (wc == 0 && fr == 0) {
        #pragma unroll
        for (int mf = 0; mf < 4; ++mf)
            #pragma unroll
            for (int m = 0; m < 4; ++m) {
                const int rr = wr * 64 + mf * 16 + quad * 4 + m;
                pmax[((size_t)bm * 128 + rr) * 8 + nb] =
                    fmaxf(redf[rr], redf[128 + rr]);
            }
    }
    #pragma unroll
    for (int mf = 0; mf < 4; ++mf)
        #pragma unroll
        for (int m = 0; m < 4; ++m) {
            const size_t row = (size_t)bm * 128 + wr * 64 + mf * 16 + quad * 4 + m;
            u16* rp = outU + row * 4096 + 1024;
            #pragma unroll
            for (int nf = 0; nf < 4; ++nf) rp[jc[nf]] = f2bf(acc[mf][nf][m]);
        }
}

// ---------------------------------------------------------------------------
// bsoft2: rstat_i = max_nb(pmax) + hw1_i; bvec = softmax(rstat) (one block)
// ---------------------------------------------------------------------------
__global__ __launch_bounds__(1024) void bsoft2(
    const float* __restrict__ pmax, const float* __restrict__ hw1,
    float* __restrict__ bvec)
{
    __shared__ float red[16];
    __shared__ float Msh, Lsh;
    const int t = threadIdx.x;
    float rs[16];
    #pragma unroll
    for (int e = 0; e < 16; ++e) {
        const int r = t + e * 1024;
        const float4 p0 = *(const float4*)(pmax + (size_t)r * 8);
        const float4 p1 = *(const float4*)(pmax + (size_t)r * 8 + 4);
        rs[e] = fmaxf(fmaxf(fmaxf(p0.x, p0.y), fmaxf(p0.z, p0.w)),
                      fmaxf(fmaxf(p1.x, p1.y), fmaxf(p1.z, p1.w))) + hw1[r];
    }
    float m = -1e30f;
    #pragma unroll
    for (int e = 0; e < 16; ++e) m = fmaxf(m, rs[e]);
    #pragma unroll
    for (int s = 1; s < 64; s <<= 1) m = fmaxf(m, __shfl_xor(m, s));
    if ((t & 63) == 0) red[t >> 6] = m;
    __syncthreads();
    if (t == 0) {
        float M = red[0];
        for (int i = 1; i < 16; ++i) M = fmaxf(M, red[i]);
        Msh = M;
    }
    __syncthreads();
    const float M = Msh;
    float l = 0.f;
    #pragma unroll
    for (int e = 0; e < 16; ++e) l += __expf(rs[e] - M);
    #pragma unroll
    for (int s = 1; s < 64; s <<= 1) l += __shfl_xor(l, s);
    if ((t & 63) == 0) red[t >> 6] = l;
    __syncthreads();
    if (t == 0) {
        float L = 0.f;
        for (int i = 0; i < 16; ++i) L += red[i];
        Lsh = L;
    }
    __syncthreads();
    const float invL = 1.f / Lsh;
    #pragma unroll
    for (int e = 0; e < 16; ++e) bvec[t + e * 1024] = __expf(rs[e] - M) * invL;
}

// ---------------------------------------------------------------------------
// h_tilde = b @ H (two-stage deterministic)
// ---------------------------------------------------------------------------
__global__ __launch_bounds__(512) void htilde_partial(
    const float* __restrict__ H, const float* __restrict__ b,
    float* __restrict__ part)
{
    const int blk = blockIdx.x;
    const int d = threadIdx.x;
    const int i0 = blk * 64;
    float s = 0.f;
    for (int rI = 0; rI < 64; ++rI)
        s += b[i0 + rI] * H[(size_t)(i0 + rI) * D_DIM + d];
    part[(size_t)blk * D_DIM + d] = s;
}

__global__ __launch_bounds__(512) void htilde_reduce(
    const float* __restrict__ part, float* __restrict__ ht)
{
    const int d = threadIdx.x;
    float s = 0.f;
    for (int p = 0; p < 256; ++p) s += part[(size_t)p * D_DIM + d];
    ht[d] = s;
}

// ---------------------------------------------------------------------------
// pv_fused: block = 64 rows x all 512 d. Phase1: stage S bf16 rows into LDS
// (slot^(r&7) source-swizzle). Phase2: in-LDS row softmax -> P. Phase3:
// AQ = P @ Utp (barrier-free, reg-pipelined B) + fused G epilogue.
// ---------------------------------------------------------------------------
__global__ __launch_bounds__(512) void pv_fused(
    u16* outU, const u16* __restrict__ Utp, const float* __restrict__ H,
    const float* __restrict__ htld)
{
    __shared__ u16 SP[64 * 1024];   // 128 KB
    const int tid = threadIdx.x, lane = tid & 63, w = tid >> 6;
    const int fr = lane & 15, quad = lane >> 4;
    const int ib = blockIdx.x * 64;

    // Phase 1: stage S rows [ib, ib+64), 16 passes x 512 lanes x 16B
    {
        const int r_off = tid >> 7;       // 0..3
        const int c8 = tid & 127;         // 16B slot within row
        #pragma unroll
        for (int p = 0; p < 16; ++p) {
            const int r = p * 4 + r_off;
            gload16(outU + (size_t)(ib + r) * 4096 + 1024 + (size_t)((c8 ^ (r & 7)) * 8),
                    SP + (size_t)p * 4096 + (size_t)tid * 8);
        }
    }
    __syncthreads();

    // Phase 2: in-place softmax; wave w owns rows [8w, 8w+8)
    #pragma unroll
    for (int rr = 0; rr < 8; ++rr) {
        const int r = w * 8 + rr;        // r&7 == rr
        u16* row = SP + (size_t)r * 1024;
        const int s0 = (lane ^ rr) * 8;
        const int s1 = ((lane + 64) ^ rr) * 8;
        bf16x8 x0 = *(bf16x8*)(row + s0);
        bf16x8 x1 = *(bf16x8*)(row + s1);
        float f0[8], f1[8];
        float mx = -1e30f;
        #pragma unroll
        for (int i = 0; i < 8; ++i) {
            f0[i] = bf2f((u16)x0[i]); f1[i] = bf2f((u16)x1[i]);
            mx = fmaxf(mx, fmaxf(f0[i], f1[i]));
        }
        #pragma unroll
        for (int s = 1; s < 64; s <<= 1) mx = fmaxf(mx, __shfl_xor(mx, s));
        float sum = 0.f;
        #pragma unroll
        for (int i = 0; i < 8; ++i) {
            f0[i] = __expf(f0[i] - mx); f1[i] = __expf(f1[i] - mx);
            sum += f0[i] + f1[i];
        }
        #pragma unroll
        for (int s = 1; s < 64; s <<= 1) sum += __shfl_xor(sum, s);
        const float inv = 1.f / sum;
        bf16x8 y0, y1;
        #pragma unroll
        for (int i = 0; i < 8; ++i) {
            y0[i] = (short)f2bf(f0[i] * inv);
            y1[i] = (short)f2bf(f1[i] * inv);
        }
        *(bf16x8*)(row + s0) = y0;
        *(bf16x8*)(row + s1) = y1;
    }
    __syncthreads();

    // Phase 3: AQ = P @ Utp; wave w owns d in [64w, 64w+64)
    f32x4 acc[4][4];
    #pragma unroll
    for (int i = 0; i < 4; ++i)
        #pragma unroll
        for (int j = 0; j < 4; ++j) acc[i][j] = (f32x4){0.f, 0.f, 0.f, 0.f};

    const u16* bp = Utp + (size_t)lane * 8;
    bf16x8 bA[4], bB[4];
    #pragma unroll
    for (int nf = 0; nf < 4; ++nf)
        bA[nf] = *(const bf16x8*)(bp + ((size_t)(w * 4 + nf) * 32) * 512);

    for (int ks = 0; ks < 32; ks += 2) {
        #pragma unroll
        for (int nf = 0; nf < 4; ++nf)
            bB[nf] = *(const bf16x8*)(bp + ((size_t)(w * 4 + nf) * 32 + ks + 1) * 512);
        bf16x8 a0[4];
        #pragma unroll
        for (int mf = 0; mf < 4; ++mf)
            a0[mf] = *(const bf16x8*)(SP + (size_t)(mf * 16 + fr) * 1024
                                         + (size_t)(((ks * 4 + quad) ^ (fr & 7)) * 8));
        #pragma unroll
        for (int mf = 0; mf < 4; ++mf)
            #pragma unroll
            for (int nf = 0; nf < 4; ++nf)
                acc[mf][nf] = __builtin_amdgcn_mfma_f32_16x16x32_bf16(
                    a0[mf], bA[nf], acc[mf][nf], 0, 0, 0);
        if (ks + 2 < 32) {
            #pragma unroll
            for (int nf = 0; nf < 4; ++nf)
                bA[nf] = *(const bf16x8*)(bp + ((size_t)(w * 4 + nf) * 32 + ks + 2) * 512);
        }
        bf16x8 a1[4];
        #pragma unroll
        for (int mf = 0; mf < 4; ++mf)
            a1[mf] = *(const bf16x8*)(SP + (size_t)(mf * 16 + fr) * 1024
                                         + (size_t)((((ks + 1) * 4 + quad) ^ (fr & 7)) * 8));
        #pragma unroll
        for (int mf = 0; mf < 4; ++mf)
            #pragma unroll
            for (int nf = 0; nf < 4; ++nf)
                acc[mf][nf] = __builtin_amdgcn_mfma_f32_16x16x32_bf16(
                    a1[mf], bB[nf], acc[mf][nf], 0, 0, 0);
    }

    // Epilogue: G = [H, AQ, H*AQ, H*h_tilde]
    float ht[4];
    #pragma unroll
    for (int nf = 0; nf < 4; ++nf) ht[nf] = htld[w * 64 + nf * 16 + fr];
    #pragma unroll
    for (int mf = 0; mf < 4; ++mf)
        #pragma unroll
        for (int m = 0; m < 4; ++m) {
            const size_t row = (size_t)ib + mf * 16 + quad * 4 + m;
            const float* hrow = H + row * D_DIM;
            float* ob = (float*)outU + row * 2048;
            #pragma unroll
            for (int nf = 0; nf < 4; ++nf) {
                const int c = w * 64 + nf * 16 + fr;
                const float h  = hrow[c];
                const float aq = acc[mf][nf][m];
                ob[c]        = h;
                ob[512 + c]  = aq;
                ob[1024 + c] = h * aq;
                ob[1536 + c] = h * ht[nf];
            }
        }
}

// ---------------------------------------------------------------------------
extern "C" void kernel_launch(void* const* d_in, const int* in_sizes, int n_in,
                              void* d_out, int out_size, void* d_ws, size_t ws_size,
                              hipStream_t stream)
{
    const float* H  = (const float*)d_in[0];
    const float* U  = (const float*)d_in[1];
    const float* Ws = (const float*)d_in[2];
    u16* outU = (u16*)d_out;

    float* uw2   = (float*)d_ws;                   // 1024
    float* hw1   = uw2 + 1024;                     // 16384
    float* bvec  = hw1 + T_ROWS;                   // 16384
    float* htld  = bvec + T_ROWS;                  // 512
    float* part  = htld + D_DIM;                   // 256*512
    float* pmax  = part + 256 * D_DIM;             // 16384*8
    u16*   Ub    = (u16*)(pmax + (size_t)T_ROWS * 8);   // 1 MB
    u16*   Utp   = Ub + (size_t)J_DIM * D_DIM;          // 1 MB

    hipLaunchKernelGGL(prep_u, dim3(J_DIM), dim3(128), 0, stream, U, Ws, uw2, Ub, Utp);
    hipLaunchKernelGGL(prep_h, dim3(T_ROWS), dim3(128), 0, stream, H, Ws, hw1, outU);
    hipLaunchKernelGGL(s_gemm, dim3(1024), dim3(256), 0, stream, outU, Ub, uw2, pmax);
    hipLaunchKernelGGL(bsoft2, dim3(1), dim3(1024), 0, stream, pmax, hw1, bvec);
    hipLaunchKernelGGL(htilde_partial, dim3(256), dim3(512), 0, stream, H, bvec, part);
    hipLaunchKernelGGL(htilde_reduce, dim3(1), dim3(512), 0, stream, part, htld);
    hipLaunchKernelGGL(pv_fused, dim3(T_ROWS / 64), dim3(512), 0, stream,
                       outU, Utp, H, htld);
}